// Round 12
// baseline (744.797 us; speedup 1.0000x reference)
//
#include <hip/hip_runtime.h>
#include <hip/hip_bf16.h>
#include <stdint.h>

// TemporalEncoderLayer: N=32, F=4096, C=256, H=8, D=32. M = N*F = 131072.
// cvt(W) -> qkv_gemm -> attn_stats(partials) -> attn_reduce -> attn_out(+LN1 -> x1 fp32 in d_out)
//        -> ffn1(gelu -> h fp32) -> ffn2(hi/lo, +x1, LN2 -> out). Deterministic (no atomics).
// Round 12 = round 11 (PASS, 724us) with qkv-only change (config class): revert to the
// round-3-proven 6-block 128x128 geometry (acc[4][4] = 64 AGPR) + __launch_bounds__(256,3)
// -> 3 waves/SIMD. Same occupancy recipe that fixed ffn1 in round 11.

#define DEVINL static __device__ __forceinline__

typedef float f32x4 __attribute__((ext_vector_type(4)));
typedef short s16x8 __attribute__((ext_vector_type(8)));

DEVINL ushort f2bf(float f) {            // RNE f32 -> bf16 (finite inputs)
  uint32_t x = __builtin_bit_cast(uint32_t, f);
  uint32_t r = x + 0x7fffu + ((x >> 16) & 1u);
  return (ushort)(r >> 16);
}
DEVINL float bfl(uint32_t u) { return __builtin_bit_cast(float, u << 16); }
DEVINL float bfh(uint32_t u) { return __builtin_bit_cast(float, u & 0xffff0000u); }
DEVINL float bf2f(ushort u)  { return __builtin_bit_cast(float, (uint32_t)u << 16); }

constexpr int LSTR = 72;   // padded LDS row stride (elems): 144B = 9*16B, 16B-aligned rows
constexpr int KVP  = 1028; // kv head stride (floats): 4112B -> head bank base 4*cb, conflict-free

// Stage a [ROWS x 64] fp32 tile into LDS as single bf16.
template<int ROWS>
DEVINL void stage_cvt(const float* __restrict__ g, int ld, ushort* lds, int tid) {
  #pragma unroll
  for (int it = 0; it < ROWS / 16; ++it) {
    int chunk = it * 256 + tid;          // float4 chunk
    int row = chunk >> 4, c4 = chunk & 15;
    float4 v = *(const float4*)(g + (size_t)row * ld + c4 * 4);
    ushort4 o; o.x = f2bf(v.x); o.y = f2bf(v.y); o.z = f2bf(v.z); o.w = f2bf(v.w);
    *(ushort4*)(lds + row * LSTR + c4 * 4) = o;
  }
}

// Stage a [ROWS x 64] fp32 tile into TWO LDS tiles: hi = bf16(v), lo = bf16(v - hi).
template<int ROWS>
DEVINL void stage_split(const float* __restrict__ g, int ld, ushort* ldsH, ushort* ldsL, int tid) {
  #pragma unroll
  for (int it = 0; it < ROWS / 16; ++it) {
    int chunk = it * 256 + tid;
    int row = chunk >> 4, c4 = chunk & 15;
    float4 v = *(const float4*)(g + (size_t)row * ld + c4 * 4);
    ushort4 h, l;
    h.x = f2bf(v.x); l.x = f2bf(v.x - bf2f(h.x));
    h.y = f2bf(v.y); l.y = f2bf(v.y - bf2f(h.y));
    h.z = f2bf(v.z); l.z = f2bf(v.z - bf2f(h.z));
    h.w = f2bf(v.w); l.w = f2bf(v.w - bf2f(h.w));
    *(ushort4*)(ldsH + row * LSTR + c4 * 4) = h;
    *(ushort4*)(ldsL + row * LSTR + c4 * 4) = l;
  }
}

DEVINL s16x8 frag_pad(const ushort* lds, int row, int ke) {   // ke in [0,64), mult of 8
  return *(const s16x8*)(lds + row * LSTR + ke);
}
DEVINL s16x8 bglob(const ushort* __restrict__ W, int row, int ke) {  // L2-resident weight frag
  return *(const s16x8*)(W + (size_t)row * 256 + ke);
}
DEVINL f32x4 mfma16(s16x8 a, s16x8 b, f32x4 c) {
  return __builtin_amdgcn_mfma_f32_16x16x32_bf16(a, b, c, 0, 0, 0);
}

__global__ void cvt_bf16(const float* __restrict__ s, ushort* __restrict__ d, int n4) {
  int i = blockIdx.x * blockDim.x + threadIdx.x;
  int stride = gridDim.x * blockDim.x;
  for (; i < n4; i += stride) {
    float4 v = ((const float4*)s)[i];
    ushort4 o; o.x = f2bf(v.x); o.y = f2bf(v.y); o.z = f2bf(v.z); o.w = f2bf(v.w);
    ((ushort4*)d)[i] = o;
  }
}

__global__ void cvt_hilo(const float* __restrict__ s, ushort* __restrict__ hi,
                         ushort* __restrict__ lo, int n) {
  int i = blockIdx.x * blockDim.x + threadIdx.x;
  if (i < n) {
    float v = s[i];
    ushort h = f2bf(v);
    hi[i] = h;
    lo[i] = f2bf(v - bf2f(h));
  }
}

// ---------- K1: qkv = x @ Wqkv^T ; q,k get elu+1 ; bf16 outputs ----------
// grid (6, 1024): 128 rows x 128 cols per block (round-3-proven geometry); (256,3) occupancy.
__global__ __launch_bounds__(256, 3)
void qkv_gemm(const float* __restrict__ X, const ushort* __restrict__ W,
              ushort* __restrict__ q, ushort* __restrict__ k, ushort* __restrict__ v) {
  __shared__ ushort As[128 * LSTR];
  const int tid = threadIdx.x, lane = tid & 63, w = tid >> 6;
  const int wm = w >> 1, wn = w & 1;
  const int nt = blockIdx.x;                 // 0..5
  const size_t m0 = (size_t)blockIdx.y * 128;
  const int n0 = nt * 128;

  f32x4 acc[4][4];
  #pragma unroll
  for (int i = 0; i < 4; ++i)
    #pragma unroll
    for (int j = 0; j < 4; ++j) acc[i][j] = (f32x4){0.f, 0.f, 0.f, 0.f};

  for (int kt = 0; kt < 4; ++kt) {
    if (kt) __syncthreads();
    stage_cvt<128>(X + m0 * 256 + kt * 64, 256, As, tid);
    __syncthreads();
    #pragma unroll
    for (int ks = 0; ks < 2; ++ks) {
      const int kl = ks * 32 + ((lane >> 4) << 3);   // local k elem
      const int ke = kt * 64 + kl;                   // global k elem
      s16x8 af[4], bfr[4];
      #pragma unroll
      for (int i = 0; i < 4; ++i) af[i] = frag_pad(As, wm * 64 + i * 16 + (lane & 15), kl);
      #pragma unroll
      for (int j = 0; j < 4; ++j) bfr[j] = bglob(W, n0 + wn * 64 + j * 16 + (lane & 15), ke);
      #pragma unroll
      for (int i = 0; i < 4; ++i)
        #pragma unroll
        for (int j = 0; j < 4; ++j) acc[i][j] = mfma16(af[i], bfr[j], acc[i][j]);
    }
  }
  ushort* dst; int col0; bool do_elu;
  if (nt < 2)      { dst = q; col0 = nt * 128; do_elu = true; }
  else if (nt < 4) { dst = k; col0 = (nt - 2) * 128; do_elu = true; }
  else             { dst = v; col0 = (nt - 4) * 128; do_elu = false; }
  #pragma unroll
  for (int j = 0; j < 4; ++j) {
    int col = wn * 64 + j * 16 + (lane & 15);
    #pragma unroll
    for (int i = 0; i < 4; ++i) {
      #pragma unroll
      for (int r = 0; r < 4; ++r) {
        int row = wm * 64 + i * 16 + ((lane >> 4) << 2) + r;
        float val = acc[i][j][r];
        if (do_elu) val = val > 0.f ? val + 1.f : __expf(val);   // elu(x)+1
        dst[(m0 + row) * 256 + (size_t)(col0 + col)] = f2bf(val);
      }
    }
  }
}

// ---------- K2: per-chunk partials of kv[n,h,m,d], ksum[n,h,d] (NO atomics) ----------
__global__ __launch_bounds__(256, 4)
void attn_stats(const ushort* __restrict__ kf, const ushort* __restrict__ vf,
                float* __restrict__ kvp, float* __restrict__ ksp) {
  __shared__ float kS[64][36];
  __shared__ float vS[64][36];
  __shared__ float kvred[4][1024];
  __shared__ float ksred[4][32];
  const int t = threadIdx.x, lane = t & 63, w = t >> 6;
  const int pair = blockIdx.x >> 3, sc = blockIdx.x & 7;
  const int n = pair >> 3, h = pair & 7;
  const size_t base_row = (size_t)n * 4096 + (size_t)sc * 512;
  const int mq = lane >> 3, dq = lane & 7;
  const int srow = t >> 2, quad = t & 3;
  float acc[4][4] = {};
  float ksacc = 0.f;

  for (int ch = 0; ch < 8; ++ch) {
    size_t gidx = (base_row + ch * 64 + srow) * 256 + h * 32 + quad * 8;
    uint4 ku = *(const uint4*)(kf + gidx);
    uint4 vu = *(const uint4*)(vf + gidx);
    if (ch) __syncthreads();
    float* kd = &kS[srow][quad * 8];
    kd[0] = bfl(ku.x); kd[1] = bfh(ku.x); kd[2] = bfl(ku.y); kd[3] = bfh(ku.y);
    kd[4] = bfl(ku.z); kd[5] = bfh(ku.z); kd[6] = bfl(ku.w); kd[7] = bfh(ku.w);
    float* vd = &vS[srow][quad * 8];
    vd[0] = bfl(vu.x); vd[1] = bfh(vu.x); vd[2] = bfl(vu.y); vd[3] = bfh(vu.y);
    vd[4] = bfl(vu.z); vd[5] = bfh(vu.z); vd[6] = bfl(vu.w); vd[7] = bfh(vu.w);
    __syncthreads();
    const int s0 = w * 16;
    #pragma unroll
    for (int s = 0; s < 16; ++s) {
      float4 vv = *(const float4*)&vS[s0 + s][mq * 4];
      float4 kk = *(const float4*)&kS[s0 + s][dq * 4];
      float vvv[4] = {vv.x, vv.y, vv.z, vv.w};
      float kkk[4] = {kk.x, kk.y, kk.z, kk.w};
      #pragma unroll
      for (int mi = 0; mi < 4; ++mi)
        #pragma unroll
        for (int di = 0; di < 4; ++di) acc[mi][di] += vvv[mi] * kkk[di];
    }
    #pragma unroll
    for (int i2 = 0; i2 < 8; ++i2) ksacc += kS[w * 16 + (lane >> 5) * 8 + i2][lane & 31];
  }
  #pragma unroll
  for (int mi = 0; mi < 4; ++mi)
    #pragma unroll
    for (int di = 0; di < 4; ++di)
      kvred[w][(mq * 4 + mi) * 32 + dq * 4 + di] = acc[mi][di];
  float kss = ksacc + __shfl_down(ksacc, 32, 64);
  if (lane < 32) ksred[w][lane] = kss;
  __syncthreads();
  for (int e = t; e < 1024; e += 256) {
    float s2 = kvred[0][e] + kvred[1][e] + kvred[2][e] + kvred[3][e];
    kvp[((size_t)pair * 8 + sc) * 1024 + e] = s2;
  }
  if (t < 32) {
    float s2 = ksred[0][t] + ksred[1][t] + ksred[2][t] + ksred[3][t];
    ksp[(pair * 8 + sc) * 32 + t] = s2;
  }
}

// ---------- K2b: reduce the 8 chunk-partials (fixed order: deterministic) ----------
__global__ __launch_bounds__(256)
void attn_reduce(const float* __restrict__ kvp, const float* __restrict__ ksp,
                 float* __restrict__ kvg, float* __restrict__ ksg) {
  const int pair = blockIdx.x, t = threadIdx.x;
  #pragma unroll
  for (int e0 = 0; e0 < 4; ++e0) {
    int e = e0 * 256 + t;
    const float* p = kvp + (size_t)pair * 8192 + e;
    float s = 0.f;
    #pragma unroll
    for (int sc = 0; sc < 8; ++sc) s += p[sc * 1024];
    kvg[pair * 1024 + e] = s;
  }
  if (t < 32) {
    const float* p = ksp + pair * 256 + t;
    float s = 0.f;
    #pragma unroll
    for (int sc = 0; sc < 8; ++sc) s += p[sc * 32];
    ksg[pair * 32 + t] = s;
  }
}

// ---------- K3: t = z*(q.kv^T); x1 = LN1(t + x) -> fp32 (d_out), staged writes ----------
// launch_bounds (256,2): VGPR cap 256 so qv[32]/u[32] live in registers (no scratch spill).
__global__ __launch_bounds__(256, 2)
void attn_out(const ushort* __restrict__ qf, const float* __restrict__ kvg,
              const float* __restrict__ ksg, const float* __restrict__ x,
              const float* __restrict__ g1, const float* __restrict__ be1,
              float* __restrict__ X1out) {
  __shared__ float pool[9216];             // phase1: kv [8][KVP]; phase2: out stage [32][288]
  __shared__ float ksS[256];
  const int t = threadIdx.x;
  const int n = blockIdx.y, rc = blockIdx.x;
  for (int i = t; i < 8192; i += 256)
    pool[(i >> 10) * KVP + (i & 1023)] = kvg[(size_t)n * 8192 + i];
  ksS[t] = ksg[n * 256 + t];
  __syncthreads();
  const int rl = t >> 3, cb = t & 7;      // row-local, head
  const size_t row = (size_t)n * 4096 + rc * 32 + rl;
  float qv[32];
  const uint4* qp = (const uint4*)(qf + row * 256 + cb * 32);
  #pragma unroll
  for (int i = 0; i < 4; ++i) {
    uint4 u4 = qp[i];
    qv[i*8+0] = bfl(u4.x); qv[i*8+1] = bfh(u4.x);
    qv[i*8+2] = bfl(u4.y); qv[i*8+3] = bfh(u4.y);
    qv[i*8+4] = bfl(u4.z); qv[i*8+5] = bfh(u4.z);
    qv[i*8+6] = bfl(u4.w); qv[i*8+7] = bfh(u4.w);
  }
  const float* ksh = &ksS[cb * 32];
  float denom = 0.f;
  #pragma unroll
  for (int d = 0; d < 32; ++d) denom += qv[d] * ksh[d];
  const float z = 1.f / (denom + 1e-6f);
  float u[32];
  const float* kvh = &pool[cb * KVP];
  #pragma unroll
  for (int m = 0; m < 32; ++m) {
    const float4* kr = (const float4*)&kvh[m * 32];
    float s = 0.f;
    #pragma unroll
    for (int d4 = 0; d4 < 8; ++d4) {
      float4 kk = kr[d4];
      s += qv[d4*4+0]*kk.x + qv[d4*4+1]*kk.y + qv[d4*4+2]*kk.z + qv[d4*4+3]*kk.w;
    }
    u[m] = z * s;
  }
  const float4* xp = (const float4*)(x + row * 256 + cb * 32);
  float ps = 0.f, pq = 0.f;
  #pragma unroll
  for (int mi = 0; mi < 8; ++mi) {
    float4 xv = xp[mi];
    float xa[4] = {xv.x, xv.y, xv.z, xv.w};
    #pragma unroll
    for (int c = 0; c < 4; ++c) {
      float uu = u[mi*4+c] + xa[c];
      u[mi*4+c] = uu; ps += uu; pq += uu * uu;
    }
  }
  // row reduction across the 8 heads = 8 consecutive lanes
  #pragma unroll
  for (int m = 1; m < 8; m <<= 1) {
    ps += __shfl_xor(ps, m, 64);
    pq += __shfl_xor(pq, m, 64);
  }
  const float mu = ps * (1.f / 256.f);
  const float var = pq * (1.f / 256.f) - mu * mu;
  const float rstd = rsqrtf(var + 1e-5f);
  const int c0 = cb * 32;
  __syncthreads();                        // everyone done reading pool (kv)
  // stage final values: [rl][cb*36 + m] (head skew 36 -> conflict-free float4 writes)
  #pragma unroll
  for (int grp = 0; grp < 8; ++grp) {
    f32x4 o;
    #pragma unroll
    for (int c = 0; c < 4; ++c) {
      int m = grp * 4 + c;
      o[c] = (u[m] - mu) * rstd * g1[c0 + m] + be1[c0 + m];
    }
    *(f32x4*)&pool[rl * 288 + cb * 36 + grp * 4] = o;
  }
  __syncthreads();
  // dense copy-out: 32 rows x 256 f32 = contiguous 32KB region
  const size_t base = ((size_t)n * 4096 + (size_t)rc * 32) * 256;
  #pragma unroll
  for (int it = 0; it < 8; ++it) {
    int fi = it * 256 + t;                 // float4 index in [0,2048)
    int r2 = fi >> 6, q4 = fi & 63;
    f32x4 v = *(const f32x4*)&pool[r2 * 288 + (q4 >> 3) * 36 + (q4 & 7) * 4];
    *(f32x4*)(X1out + base + (size_t)fi * 4) = v;
  }
}

// ---------- K4: h = gelu(x1 @ W1^T + b1) -> fp32; 128 rows x 128 cols (N-split) ----------
// (256,3): 3 waves/SIMD. 2-MFMA scheme: x1 hi/lo x W1-hi (W1-lo term dropped; ~2e-3 on h).
__global__ __launch_bounds__(256, 3)
void ffn1_gemm(const float* __restrict__ X1, const ushort* __restrict__ Wh,
               const float* __restrict__ bias, float* __restrict__ Hout) {
  __shared__ ushort AsH[128 * LSTR];
  __shared__ ushort AsL[128 * LSTR];
  const int tid = threadIdx.x, lane = tid & 63, w = tid >> 6;
  const size_t m0 = (size_t)blockIdx.y * 128;
  const int n0 = blockIdx.x * 128;
  f32x4 acc[2][8];
  #pragma unroll
  for (int i = 0; i < 2; ++i)
    #pragma unroll
    for (int j = 0; j < 8; ++j) acc[i][j] = (f32x4){0.f, 0.f, 0.f, 0.f};
  for (int kt = 0; kt < 4; ++kt) {
    if (kt) __syncthreads();
    stage_split<128>(X1 + m0 * 256 + kt * 64, 256, AsH, AsL, tid);
    __syncthreads();
    #pragma unroll
    for (int ks = 0; ks < 2; ++ks) {
      const int kl = ks * 32 + ((lane >> 4) << 3);
      const int ke = kt * 64 + kl;
      s16x8 a0h = frag_pad(AsH, w * 32 + (lane & 15), kl);
      s16x8 a1h = frag_pad(AsH, w * 32 + 16 + (lane & 15), kl);
      s16x8 a0l = frag_pad(AsL, w * 32 + (lane & 15), kl);
      s16x8 a1l = frag_pad(AsL, w * 32 + 16 + (lane & 15), kl);
      #pragma unroll
      for (int j = 0; j < 8; ++j) {
        s16x8 wh = bglob(Wh, n0 + j * 16 + (lane & 15), ke);
        acc[0][j] = mfma16(a0h, wh, mfma16(a0l, wh, acc[0][j]));
        acc[1][j] = mfma16(a1h, wh, mfma16(a1l, wh, acc[1][j]));
      }
    }
  }
  #pragma unroll
  for (int i = 0; i < 2; ++i) {
    #pragma unroll
    for (int r = 0; r < 4; ++r) {
      const int row = w * 32 + i * 16 + ((lane >> 4) << 2) + r;
      const size_t grow = (m0 + row) * 256;
      #pragma unroll
      for (int j = 0; j < 8; ++j) {
        int c = n0 + j * 16 + (lane & 15);
        float val = acc[i][j][r] + bias[c];
        val = 0.5f * val * (1.f + erff(val * 0.70710678118654752f));
        Hout[grow + c] = val;
      }
    }
  }
}

// ---------- K5: y = h @ W2^T + b2; out = LN2(y + x1) -> fp32 (round-8 exact) ----------
__global__ __launch_bounds__(256, 2)
void ffn2_ln(const float* __restrict__ Hf, const ushort* __restrict__ Wh,
             const ushort* __restrict__ Wl, const float* __restrict__ X1,
             const float* __restrict__ b2, const float* __restrict__ g2,
             const float* __restrict__ be2, float* __restrict__ out) {
  __shared__ ushort AsH[128 * LSTR];
  __shared__ ushort AsL[128 * LSTR];
  const int tid = threadIdx.x, lane = tid & 63, w = tid >> 6;
  const size_t m0 = (size_t)blockIdx.x * 128;
  f32x4 acc[2][16];
  #pragma unroll
  for (int i = 0; i < 2; ++i)
    #pragma unroll
    for (int j = 0; j < 16; ++j) acc[i][j] = (f32x4){0.f, 0.f, 0.f, 0.f};
  for (int kt = 0; kt < 4; ++kt) {
    if (kt) __syncthreads();
    stage_split<128>(Hf + m0 * 256 + kt * 64, 256, AsH, AsL, tid);
    __syncthreads();
    #pragma unroll
    for (int ks = 0; ks < 2; ++ks) {
      const int kl = ks * 32 + ((lane >> 4) << 3);
      const int ke = kt * 64 + kl;
      s16x8 a0h = frag_pad(AsH, w * 32 + (lane & 15), kl);
      s16x8 a1h = frag_pad(AsH, w * 32 + 16 + (lane & 15), kl);
      s16x8 a0l = frag_pad(AsL, w * 32 + (lane & 15), kl);
      s16x8 a1l = frag_pad(AsL, w * 32 + 16 + (lane & 15), kl);
      #pragma unroll
      for (int j = 0; j < 16; ++j) {
        s16x8 wh = bglob(Wh, j * 16 + (lane & 15), ke);
        s16x8 wl = bglob(Wl, j * 16 + (lane & 15), ke);
        acc[0][j] = mfma16(a0h, wh, mfma16(a0h, wl, mfma16(a0l, wh, acc[0][j])));
        acc[1][j] = mfma16(a1h, wh, mfma16(a1h, wl, mfma16(a1l, wh, acc[1][j])));
      }
    }
  }
  // epilogue: +b2, +x1(fp32) residual, LayerNorm over 256 cols (16-lane groups)
  #pragma unroll
  for (int i = 0; i < 2; ++i) {
    #pragma unroll
    for (int r = 0; r < 4; ++r) {
      const int row = w * 32 + i * 16 + ((lane >> 4) << 2) + r;
      const size_t grow = (m0 + row) * 256;
      float u[16]; float s = 0.f, sq = 0.f;
      #pragma unroll
      for (int j = 0; j < 16; ++j) {
        int c = j * 16 + (lane & 15);
        float val = acc[i][j][r] + b2[c] + X1[grow + c];
        u[j] = val; s += val; sq += val * val;
      }
      #pragma unroll
      for (int m = 1; m < 16; m <<= 1) {
        s  += __shfl_xor(s, m, 64);
        sq += __shfl_xor(sq, m, 64);
      }
      const float mu = s * (1.f / 256.f);
      const float var = sq * (1.f / 256.f) - mu * mu;
      const float rstd = rsqrtf(var + 1e-5f);
      #pragma unroll
      for (int j = 0; j < 16; ++j) {
        int c = j * 16 + (lane & 15);
        out[grow + c] = (u[j] - mu) * rstd * g2[c] + be2[c];
      }
    }
  }
}

extern "C" void kernel_launch(void* const* d_in, const int* in_sizes, int n_in,
                              void* d_out, int out_size, void* d_ws, size_t ws_size,
                              hipStream_t stream) {
  const float* x    = (const float*)d_in[0];
  const float* Wqkv = (const float*)d_in[1];
  const float* ln1g = (const float*)d_in[2];
  const float* ln1b = (const float*)d_in[3];
  const float* W1   = (const float*)d_in[4];
  const float* b1   = (const float*)d_in[5];
  const float* W2   = (const float*)d_in[6];
  const float* b2   = (const float*)d_in[7];
  const float* ln2g = (const float*)d_in[8];
  const float* ln2b = (const float*)d_in[9];
  float* out = (float*)d_out;
  float* x1  = (float*)d_out;              // x1 fp32 lives in d_out (rewritten by ffn2_ln)
  char* ws = (char*)d_ws;
  const size_t MB = 1024 * 1024;
  ushort* qb  = (ushort*)(ws);             // 64MB  q (bf16); dead after attn_out
  ushort* kb  = (ushort*)(ws + 64 * MB);   // 64MB  k (bf16); dead after attn_stats
  ushort* vb  = (ushort*)(ws + 128 * MB);  // 64MB  v (bf16); dead after attn_stats
  float*  hf  = (float*)(ws);              // 128MB h fp32 — reuses qb+kb (both dead)
  float*  kvp = (float*)(ws + 192 * MB);   // 8MB   kv partials [256 pairs][8 sc][1024]
  float*  ksp = (float*)(ws + 200 * MB);   // 256KB ksum partials [256][8][32]
  float*  kvg = (float*)(ws + 201 * MB);   // 1MB   kv reduced [256][1024]
  float*  ksg = (float*)(ws + 202 * MB);   // 32KB  ksum reduced [256][32]
  ushort* wqb = (ushort*)(ws + 203 * MB);  // 384KB Wqkv bf16
  ushort* w1h = (ushort*)(ws + 204 * MB);  // 4x128KB: W1 hi/lo, W2 hi/lo
  ushort* w1l = w1h + 65536;
  ushort* w2h = w1h + 131072;
  ushort* w2l = w1h + 196608;

  cvt_bf16<<<192, 256, 0, stream>>>(Wqkv, wqb, 196608 / 4);
  cvt_hilo<<<256, 256, 0, stream>>>(W1, w1h, w1l, 65536);
  cvt_hilo<<<256, 256, 0, stream>>>(W2, w2h, w2l, 65536);

  qkv_gemm<<<dim3(6, 1024), 256, 0, stream>>>(x, wqb, qb, kb, vb);
  attn_stats<<<2048, 256, 0, stream>>>(kb, vb, kvp, ksp);
  attn_reduce<<<256, 256, 0, stream>>>(kvp, ksp, kvg, ksg);
  attn_out<<<dim3(128, 32), 256, 0, stream>>>(qb, kvg, ksg, x, ln1g, ln1b, x1);
  ffn1_gemm<<<dim3(2, 1024), 256, 0, stream>>>(x1, w1h, b1, hf);
  ffn2_ln<<<1024, 256, 0, stream>>>(hf, w2h, w2l, x1, b2, ln2g, ln2b, out);
}

// Round 13
// 712.799 us; speedup vs baseline: 1.0449x; 1.0449x over previous
//
#include <hip/hip_runtime.h>
#include <hip/hip_bf16.h>
#include <stdint.h>

// TemporalEncoderLayer: N=32, F=4096, C=256, H=8, D=32. M = N*F = 131072.
// cvt(W) -> qkv_gemm -> attn_stats(partials) -> attn_reduce -> attn_out(+LN1 -> x1 fp32 in d_out)
//        -> ffn1(gelu -> h fp32) -> ffn2(+x1, LN2 -> out). Deterministic (no atomics).
// Round 13 = round 11 (PASS, 724us) + ffn2 wl-term drop (same arithmetic-class change that
// worked on ffn1 in r11). qkv reverted to the r11-proven 3-block geometry (r12's 6-block
// N-split doubled x fetch and was a net loss).

#define DEVINL static __device__ __forceinline__

typedef float f32x4 __attribute__((ext_vector_type(4)));
typedef short s16x8 __attribute__((ext_vector_type(8)));

DEVINL ushort f2bf(float f) {            // RNE f32 -> bf16 (finite inputs)
  uint32_t x = __builtin_bit_cast(uint32_t, f);
  uint32_t r = x + 0x7fffu + ((x >> 16) & 1u);
  return (ushort)(r >> 16);
}
DEVINL float bfl(uint32_t u) { return __builtin_bit_cast(float, u << 16); }
DEVINL float bfh(uint32_t u) { return __builtin_bit_cast(float, u & 0xffff0000u); }
DEVINL float bf2f(ushort u)  { return __builtin_bit_cast(float, (uint32_t)u << 16); }

constexpr int LSTR = 72;   // padded LDS row stride (elems): 144B = 9*16B, 16B-aligned rows
constexpr int KVP  = 1028; // kv head stride (floats): 4112B -> head bank base 4*cb, conflict-free

// Stage a [ROWS x 64] fp32 tile into LDS as single bf16.
template<int ROWS>
DEVINL void stage_cvt(const float* __restrict__ g, int ld, ushort* lds, int tid) {
  #pragma unroll
  for (int it = 0; it < ROWS / 16; ++it) {
    int chunk = it * 256 + tid;          // float4 chunk
    int row = chunk >> 4, c4 = chunk & 15;
    float4 v = *(const float4*)(g + (size_t)row * ld + c4 * 4);
    ushort4 o; o.x = f2bf(v.x); o.y = f2bf(v.y); o.z = f2bf(v.z); o.w = f2bf(v.w);
    *(ushort4*)(lds + row * LSTR + c4 * 4) = o;
  }
}

// Stage a [ROWS x 64] fp32 tile into TWO LDS tiles: hi = bf16(v), lo = bf16(v - hi).
template<int ROWS>
DEVINL void stage_split(const float* __restrict__ g, int ld, ushort* ldsH, ushort* ldsL, int tid) {
  #pragma unroll
  for (int it = 0; it < ROWS / 16; ++it) {
    int chunk = it * 256 + tid;
    int row = chunk >> 4, c4 = chunk & 15;
    float4 v = *(const float4*)(g + (size_t)row * ld + c4 * 4);
    ushort4 h, l;
    h.x = f2bf(v.x); l.x = f2bf(v.x - bf2f(h.x));
    h.y = f2bf(v.y); l.y = f2bf(v.y - bf2f(h.y));
    h.z = f2bf(v.z); l.z = f2bf(v.z - bf2f(h.z));
    h.w = f2bf(v.w); l.w = f2bf(v.w - bf2f(h.w));
    *(ushort4*)(ldsH + row * LSTR + c4 * 4) = h;
    *(ushort4*)(ldsL + row * LSTR + c4 * 4) = l;
  }
}

DEVINL s16x8 frag_pad(const ushort* lds, int row, int ke) {   // ke in [0,64), mult of 8
  return *(const s16x8*)(lds + row * LSTR + ke);
}
DEVINL s16x8 bglob(const ushort* __restrict__ W, int row, int ke) {  // L2-resident weight frag
  return *(const s16x8*)(W + (size_t)row * 256 + ke);
}
DEVINL f32x4 mfma16(s16x8 a, s16x8 b, f32x4 c) {
  return __builtin_amdgcn_mfma_f32_16x16x32_bf16(a, b, c, 0, 0, 0);
}

__global__ void cvt_bf16(const float* __restrict__ s, ushort* __restrict__ d, int n4) {
  int i = blockIdx.x * blockDim.x + threadIdx.x;
  int stride = gridDim.x * blockDim.x;
  for (; i < n4; i += stride) {
    float4 v = ((const float4*)s)[i];
    ushort4 o; o.x = f2bf(v.x); o.y = f2bf(v.y); o.z = f2bf(v.z); o.w = f2bf(v.w);
    ((ushort4*)d)[i] = o;
  }
}

// ---------- K1: qkv = x @ Wqkv^T ; q,k get elu+1 ; bf16 outputs ----------
// grid (3, 1024): nt = 0/1/2 -> q/k/v, each block computes 128 rows x 256 cols (r11-proven).
__global__ __launch_bounds__(256, 2)
void qkv_gemm(const float* __restrict__ X, const ushort* __restrict__ W,
              ushort* __restrict__ q, ushort* __restrict__ k, ushort* __restrict__ v) {
  __shared__ ushort As[128 * LSTR];
  const int tid = threadIdx.x, lane = tid & 63, w = tid >> 6;
  const int wm = w >> 1, wn = w & 1;
  const int nt = blockIdx.x;                 // 0..2
  const size_t m0 = (size_t)blockIdx.y * 128;
  const int n0 = nt * 256;

  f32x4 acc[4][8];
  #pragma unroll
  for (int i = 0; i < 4; ++i)
    #pragma unroll
    for (int j = 0; j < 8; ++j) acc[i][j] = (f32x4){0.f, 0.f, 0.f, 0.f};

  for (int kt = 0; kt < 4; ++kt) {
    if (kt) __syncthreads();
    stage_cvt<128>(X + m0 * 256 + kt * 64, 256, As, tid);
    __syncthreads();
    #pragma unroll
    for (int ks = 0; ks < 2; ++ks) {
      const int kl = ks * 32 + ((lane >> 4) << 3);   // local k elem
      const int ke = kt * 64 + kl;                   // global k elem
      s16x8 af[4];
      #pragma unroll
      for (int i = 0; i < 4; ++i) af[i] = frag_pad(As, wm * 64 + i * 16 + (lane & 15), kl);
      #pragma unroll
      for (int j = 0; j < 8; ++j) {
        s16x8 bfr = bglob(W, n0 + wn * 128 + j * 16 + (lane & 15), ke);
        #pragma unroll
        for (int i = 0; i < 4; ++i) acc[i][j] = mfma16(af[i], bfr, acc[i][j]);
      }
    }
  }
  ushort* dst = (nt == 0) ? q : (nt == 1) ? k : v;
  const bool do_elu = (nt != 2);
  #pragma unroll
  for (int j = 0; j < 8; ++j) {
    int col = wn * 128 + j * 16 + (lane & 15);
    #pragma unroll
    for (int i = 0; i < 4; ++i) {
      #pragma unroll
      for (int r = 0; r < 4; ++r) {
        int row = wm * 64 + i * 16 + ((lane >> 4) << 2) + r;
        float val = acc[i][j][r];
        if (do_elu) val = val > 0.f ? val + 1.f : __expf(val);   // elu(x)+1
        dst[(m0 + row) * 256 + (size_t)col] = f2bf(val);
      }
    }
  }
}

// ---------- K2: per-chunk partials of kv[n,h,m,d], ksum[n,h,d] (NO atomics) ----------
__global__ __launch_bounds__(256, 4)
void attn_stats(const ushort* __restrict__ kf, const ushort* __restrict__ vf,
                float* __restrict__ kvp, float* __restrict__ ksp) {
  __shared__ float kS[64][36];
  __shared__ float vS[64][36];
  __shared__ float kvred[4][1024];
  __shared__ float ksred[4][32];
  const int t = threadIdx.x, lane = t & 63, w = t >> 6;
  const int pair = blockIdx.x >> 3, sc = blockIdx.x & 7;
  const int n = pair >> 3, h = pair & 7;
  const size_t base_row = (size_t)n * 4096 + (size_t)sc * 512;
  const int mq = lane >> 3, dq = lane & 7;
  const int srow = t >> 2, quad = t & 3;
  float acc[4][4] = {};
  float ksacc = 0.f;

  for (int ch = 0; ch < 8; ++ch) {
    size_t gidx = (base_row + ch * 64 + srow) * 256 + h * 32 + quad * 8;
    uint4 ku = *(const uint4*)(kf + gidx);
    uint4 vu = *(const uint4*)(vf + gidx);
    if (ch) __syncthreads();
    float* kd = &kS[srow][quad * 8];
    kd[0] = bfl(ku.x); kd[1] = bfh(ku.x); kd[2] = bfl(ku.y); kd[3] = bfh(ku.y);
    kd[4] = bfl(ku.z); kd[5] = bfh(ku.z); kd[6] = bfl(ku.w); kd[7] = bfh(ku.w);
    float* vd = &vS[srow][quad * 8];
    vd[0] = bfl(vu.x); vd[1] = bfh(vu.x); vd[2] = bfl(vu.y); vd[3] = bfh(vu.y);
    vd[4] = bfl(vu.z); vd[5] = bfh(vu.z); vd[6] = bfl(vu.w); vd[7] = bfh(vu.w);
    __syncthreads();
    const int s0 = w * 16;
    #pragma unroll
    for (int s = 0; s < 16; ++s) {
      float4 vv = *(const float4*)&vS[s0 + s][mq * 4];
      float4 kk = *(const float4*)&kS[s0 + s][dq * 4];
      float vvv[4] = {vv.x, vv.y, vv.z, vv.w};
      float kkk[4] = {kk.x, kk.y, kk.z, kk.w};
      #pragma unroll
      for (int mi = 0; mi < 4; ++mi)
        #pragma unroll
        for (int di = 0; di < 4; ++di) acc[mi][di] += vvv[mi] * kkk[di];
    }
    #pragma unroll
    for (int i2 = 0; i2 < 8; ++i2) ksacc += kS[w * 16 + (lane >> 5) * 8 + i2][lane & 31];
  }
  #pragma unroll
  for (int mi = 0; mi < 4; ++mi)
    #pragma unroll
    for (int di = 0; di < 4; ++di)
      kvred[w][(mq * 4 + mi) * 32 + dq * 4 + di] = acc[mi][di];
  float kss = ksacc + __shfl_down(ksacc, 32, 64);
  if (lane < 32) ksred[w][lane] = kss;
  __syncthreads();
  for (int e = t; e < 1024; e += 256) {
    float s2 = kvred[0][e] + kvred[1][e] + kvred[2][e] + kvred[3][e];
    kvp[((size_t)pair * 8 + sc) * 1024 + e] = s2;
  }
  if (t < 32) {
    float s2 = ksred[0][t] + ksred[1][t] + ksred[2][t] + ksred[3][t];
    ksp[(pair * 8 + sc) * 32 + t] = s2;
  }
}

// ---------- K2b: reduce the 8 chunk-partials (fixed order: deterministic) ----------
__global__ __launch_bounds__(256)
void attn_reduce(const float* __restrict__ kvp, const float* __restrict__ ksp,
                 float* __restrict__ kvg, float* __restrict__ ksg) {
  const int pair = blockIdx.x, t = threadIdx.x;
  #pragma unroll
  for (int e0 = 0; e0 < 4; ++e0) {
    int e = e0 * 256 + t;
    const float* p = kvp + (size_t)pair * 8192 + e;
    float s = 0.f;
    #pragma unroll
    for (int sc = 0; sc < 8; ++sc) s += p[sc * 1024];
    kvg[pair * 1024 + e] = s;
  }
  if (t < 32) {
    const float* p = ksp + pair * 256 + t;
    float s = 0.f;
    #pragma unroll
    for (int sc = 0; sc < 8; ++sc) s += p[sc * 32];
    ksg[pair * 32 + t] = s;
  }
}

// ---------- K3: t = z*(q.kv^T); x1 = LN1(t + x) -> fp32 (d_out), staged writes ----------
// launch_bounds (256,2): VGPR cap 256 so qv[32]/u[32] live in registers (no scratch spill).
__global__ __launch_bounds__(256, 2)
void attn_out(const ushort* __restrict__ qf, const float* __restrict__ kvg,
              const float* __restrict__ ksg, const float* __restrict__ x,
              const float* __restrict__ g1, const float* __restrict__ be1,
              float* __restrict__ X1out) {
  __shared__ float pool[9216];             // phase1: kv [8][KVP]; phase2: out stage [32][288]
  __shared__ float ksS[256];
  const int t = threadIdx.x;
  const int n = blockIdx.y, rc = blockIdx.x;
  for (int i = t; i < 8192; i += 256)
    pool[(i >> 10) * KVP + (i & 1023)] = kvg[(size_t)n * 8192 + i];
  ksS[t] = ksg[n * 256 + t];
  __syncthreads();
  const int rl = t >> 3, cb = t & 7;      // row-local, head
  const size_t row = (size_t)n * 4096 + rc * 32 + rl;
  float qv[32];
  const uint4* qp = (const uint4*)(qf + row * 256 + cb * 32);
  #pragma unroll
  for (int i = 0; i < 4; ++i) {
    uint4 u4 = qp[i];
    qv[i*8+0] = bfl(u4.x); qv[i*8+1] = bfh(u4.x);
    qv[i*8+2] = bfl(u4.y); qv[i*8+3] = bfh(u4.y);
    qv[i*8+4] = bfl(u4.z); qv[i*8+5] = bfh(u4.z);
    qv[i*8+6] = bfl(u4.w); qv[i*8+7] = bfh(u4.w);
  }
  const float* ksh = &ksS[cb * 32];
  float denom = 0.f;
  #pragma unroll
  for (int d = 0; d < 32; ++d) denom += qv[d] * ksh[d];
  const float z = 1.f / (denom + 1e-6f);
  float u[32];
  const float* kvh = &pool[cb * KVP];
  #pragma unroll
  for (int m = 0; m < 32; ++m) {
    const float4* kr = (const float4*)&kvh[m * 32];
    float s = 0.f;
    #pragma unroll
    for (int d4 = 0; d4 < 8; ++d4) {
      float4 kk = kr[d4];
      s += qv[d4*4+0]*kk.x + qv[d4*4+1]*kk.y + qv[d4*4+2]*kk.z + qv[d4*4+3]*kk.w;
    }
    u[m] = z * s;
  }
  const float4* xp = (const float4*)(x + row * 256 + cb * 32);
  float ps = 0.f, pq = 0.f;
  #pragma unroll
  for (int mi = 0; mi < 8; ++mi) {
    float4 xv = xp[mi];
    float xa[4] = {xv.x, xv.y, xv.z, xv.w};
    #pragma unroll
    for (int c = 0; c < 4; ++c) {
      float uu = u[mi*4+c] + xa[c];
      u[mi*4+c] = uu; ps += uu; pq += uu * uu;
    }
  }
  // row reduction across the 8 heads = 8 consecutive lanes
  #pragma unroll
  for (int m = 1; m < 8; m <<= 1) {
    ps += __shfl_xor(ps, m, 64);
    pq += __shfl_xor(pq, m, 64);
  }
  const float mu = ps * (1.f / 256.f);
  const float var = pq * (1.f / 256.f) - mu * mu;
  const float rstd = rsqrtf(var + 1e-5f);
  const int c0 = cb * 32;
  __syncthreads();                        // everyone done reading pool (kv)
  // stage final values: [rl][cb*36 + m] (head skew 36 -> conflict-free float4 writes)
  #pragma unroll
  for (int grp = 0; grp < 8; ++grp) {
    f32x4 o;
    #pragma unroll
    for (int c = 0; c < 4; ++c) {
      int m = grp * 4 + c;
      o[c] = (u[m] - mu) * rstd * g1[c0 + m] + be1[c0 + m];
    }
    *(f32x4*)&pool[rl * 288 + cb * 36 + grp * 4] = o;
  }
  __syncthreads();
  // dense copy-out: 32 rows x 256 f32 = contiguous 32KB region
  const size_t base = ((size_t)n * 4096 + (size_t)rc * 32) * 256;
  #pragma unroll
  for (int it = 0; it < 8; ++it) {
    int fi = it * 256 + t;                 // float4 index in [0,2048)
    int r2 = fi >> 6, q4 = fi & 63;
    f32x4 v = *(const f32x4*)&pool[r2 * 288 + (q4 >> 3) * 36 + (q4 & 7) * 4];
    *(f32x4*)(X1out + base + (size_t)fi * 4) = v;
  }
}

// ---------- K4: h = gelu(x1 @ W1^T + b1) -> fp32; 128 rows x 128 cols (N-split) ----------
// (256,3): 3 waves/SIMD. 2-MFMA scheme: x1 hi/lo x W1-hi.
__global__ __launch_bounds__(256, 3)
void ffn1_gemm(const float* __restrict__ X1, const ushort* __restrict__ Wh,
               const float* __restrict__ bias, float* __restrict__ Hout) {
  __shared__ ushort AsH[128 * LSTR];
  __shared__ ushort AsL[128 * LSTR];
  const int tid = threadIdx.x, lane = tid & 63, w = tid >> 6;
  const size_t m0 = (size_t)blockIdx.y * 128;
  const int n0 = blockIdx.x * 128;
  f32x4 acc[2][8];
  #pragma unroll
  for (int i = 0; i < 2; ++i)
    #pragma unroll
    for (int j = 0; j < 8; ++j) acc[i][j] = (f32x4){0.f, 0.f, 0.f, 0.f};
  for (int kt = 0; kt < 4; ++kt) {
    if (kt) __syncthreads();
    stage_split<128>(X1 + m0 * 256 + kt * 64, 256, AsH, AsL, tid);
    __syncthreads();
    #pragma unroll
    for (int ks = 0; ks < 2; ++ks) {
      const int kl = ks * 32 + ((lane >> 4) << 3);
      const int ke = kt * 64 + kl;
      s16x8 a0h = frag_pad(AsH, w * 32 + (lane & 15), kl);
      s16x8 a1h = frag_pad(AsH, w * 32 + 16 + (lane & 15), kl);
      s16x8 a0l = frag_pad(AsL, w * 32 + (lane & 15), kl);
      s16x8 a1l = frag_pad(AsL, w * 32 + 16 + (lane & 15), kl);
      #pragma unroll
      for (int j = 0; j < 8; ++j) {
        s16x8 wh = bglob(Wh, n0 + j * 16 + (lane & 15), ke);
        acc[0][j] = mfma16(a0h, wh, mfma16(a0l, wh, acc[0][j]));
        acc[1][j] = mfma16(a1h, wh, mfma16(a1l, wh, acc[1][j]));
      }
    }
  }
  #pragma unroll
  for (int i = 0; i < 2; ++i) {
    #pragma unroll
    for (int r = 0; r < 4; ++r) {
      const int row = w * 32 + i * 16 + ((lane >> 4) << 2) + r;
      const size_t grow = (m0 + row) * 256;
      #pragma unroll
      for (int j = 0; j < 8; ++j) {
        int c = n0 + j * 16 + (lane & 15);
        float val = acc[i][j][r] + bias[c];
        val = 0.5f * val * (1.f + erff(val * 0.70710678118654752f));
        Hout[grow + c] = val;
      }
    }
  }
}

// ---------- K5: y = h @ W2^T + b2; out = LN2(y + x1) -> fp32 ----------
// 2-MFMA scheme: h hi/lo x W2-hi (W2-lo term dropped, mirroring ffn1's r11 change).
__global__ __launch_bounds__(256, 2)
void ffn2_ln(const float* __restrict__ Hf, const ushort* __restrict__ Wh,
             const float* __restrict__ X1, const float* __restrict__ b2,
             const float* __restrict__ g2, const float* __restrict__ be2,
             float* __restrict__ out) {
  __shared__ ushort AsH[128 * LSTR];
  __shared__ ushort AsL[128 * LSTR];
  const int tid = threadIdx.x, lane = tid & 63, w = tid >> 6;
  const size_t m0 = (size_t)blockIdx.x * 128;
  f32x4 acc[2][16];
  #pragma unroll
  for (int i = 0; i < 2; ++i)
    #pragma unroll
    for (int j = 0; j < 16; ++j) acc[i][j] = (f32x4){0.f, 0.f, 0.f, 0.f};
  for (int kt = 0; kt < 4; ++kt) {
    if (kt) __syncthreads();
    stage_split<128>(Hf + m0 * 256 + kt * 64, 256, AsH, AsL, tid);
    __syncthreads();
    #pragma unroll
    for (int ks = 0; ks < 2; ++ks) {
      const int kl = ks * 32 + ((lane >> 4) << 3);
      const int ke = kt * 64 + kl;
      s16x8 a0h = frag_pad(AsH, w * 32 + (lane & 15), kl);
      s16x8 a1h = frag_pad(AsH, w * 32 + 16 + (lane & 15), kl);
      s16x8 a0l = frag_pad(AsL, w * 32 + (lane & 15), kl);
      s16x8 a1l = frag_pad(AsL, w * 32 + 16 + (lane & 15), kl);
      #pragma unroll
      for (int j = 0; j < 16; ++j) {
        s16x8 wh = bglob(Wh, j * 16 + (lane & 15), ke);
        acc[0][j] = mfma16(a0h, wh, mfma16(a0l, wh, acc[0][j]));
        acc[1][j] = mfma16(a1h, wh, mfma16(a1l, wh, acc[1][j]));
      }
    }
  }
  // epilogue: +b2, +x1(fp32) residual, LayerNorm over 256 cols (16-lane groups)
  #pragma unroll
  for (int i = 0; i < 2; ++i) {
    #pragma unroll
    for (int r = 0; r < 4; ++r) {
      const int row = w * 32 + i * 16 + ((lane >> 4) << 2) + r;
      const size_t grow = (m0 + row) * 256;
      float u[16]; float s = 0.f, sq = 0.f;
      #pragma unroll
      for (int j = 0; j < 16; ++j) {
        int c = j * 16 + (lane & 15);
        float val = acc[i][j][r] + b2[c] + X1[grow + c];
        u[j] = val; s += val; sq += val * val;
      }
      #pragma unroll
      for (int m = 1; m < 16; m <<= 1) {
        s  += __shfl_xor(s, m, 64);
        sq += __shfl_xor(sq, m, 64);
      }
      const float mu = s * (1.f / 256.f);
      const float var = sq * (1.f / 256.f) - mu * mu;
      const float rstd = rsqrtf(var + 1e-5f);
      #pragma unroll
      for (int j = 0; j < 16; ++j) {
        int c = j * 16 + (lane & 15);
        out[grow + c] = (u[j] - mu) * rstd * g2[c] + be2[c];
      }
    }
  }
}

extern "C" void kernel_launch(void* const* d_in, const int* in_sizes, int n_in,
                              void* d_out, int out_size, void* d_ws, size_t ws_size,
                              hipStream_t stream) {
  const float* x    = (const float*)d_in[0];
  const float* Wqkv = (const float*)d_in[1];
  const float* ln1g = (const float*)d_in[2];
  const float* ln1b = (const float*)d_in[3];
  const float* W1   = (const float*)d_in[4];
  const float* b1   = (const float*)d_in[5];
  const float* W2   = (const float*)d_in[6];
  const float* b2   = (const float*)d_in[7];
  const float* ln2g = (const float*)d_in[8];
  const float* ln2b = (const float*)d_in[9];
  float* out = (float*)d_out;
  float* x1  = (float*)d_out;              // x1 fp32 lives in d_out (rewritten by ffn2_ln)
  char* ws = (char*)d_ws;
  const size_t MB = 1024 * 1024;
  ushort* qb  = (ushort*)(ws);             // 64MB  q (bf16); dead after attn_out
  ushort* kb  = (ushort*)(ws + 64 * MB);   // 64MB  k (bf16); dead after attn_stats
  ushort* vb  = (ushort*)(ws + 128 * MB);  // 64MB  v (bf16); dead after attn_stats
  float*  hf  = (float*)(ws);              // 128MB h fp32 — reuses qb+kb (both dead)
  float*  kvp = (float*)(ws + 192 * MB);   // 8MB   kv partials [256 pairs][8 sc][1024]
  float*  ksp = (float*)(ws + 200 * MB);   // 256KB ksum partials [256][8][32]
  float*  kvg = (float*)(ws + 201 * MB);   // 1MB   kv reduced [256][1024]
  float*  ksg = (float*)(ws + 202 * MB);   // 32KB  ksum reduced [256][32]
  ushort* wqb = (ushort*)(ws + 203 * MB);  // 384KB Wqkv bf16
  ushort* w1h = (ushort*)(ws + 204 * MB);  // 128KB W1 bf16
  ushort* w2h = w1h + 65536;               // 128KB W2 bf16

  cvt_bf16<<<192, 256, 0, stream>>>(Wqkv, wqb, 196608 / 4);
  cvt_bf16<<<64, 256, 0, stream>>>(W1, w1h, 65536 / 4);
  cvt_bf16<<<64, 256, 0, stream>>>(W2, w2h, 65536 / 4);

  qkv_gemm<<<dim3(3, 1024), 256, 0, stream>>>(x, wqb, qb, kb, vb);
  attn_stats<<<2048, 256, 0, stream>>>(kb, vb, kvp, ksp);
  attn_reduce<<<256, 256, 0, stream>>>(kvp, ksp, kvg, ksg);
  attn_out<<<dim3(128, 32), 256, 0, stream>>>(qb, kvg, ksg, x, ln1g, ln1b, x1);
  ffn1_gemm<<<dim3(2, 1024), 256, 0, stream>>>(x1, w1h, b1, hf);
  ffn2_ln<<<1024, 256, 0, stream>>>(hf, w2h, x1, b2, ln2g, ln2b, out);
}